// Round 8
// baseline (17.910 us; speedup 1.0000x reference)
//
#include <hip/hip_runtime.h>

// Forward output of the reference == hard top-k0 binary mask (straight-through
// (hard-soft)+soft == hard exactly in fp32; top-k0 set of soft == top-k0 set
// of x since clip(x+nu) is monotone). Tie-break for exact fp32 duplicates:
// lowest index first (matches jax.lax.top_k).
//
// 512-thread block (8 waves) per TWO rows (grid = bs/2): all 4 row-loads
// issued up-front so row-1 HBM time hides under row-0 compute. 8 keys/lane in
// registers. Radix select: 2 histogram passes fix the top-16-bit prefix
// (pass-0 into 16 replicated copies: hot byte = sign|exp[7:1] -> same-address
// LDS atomic serialization without replicas); survivors (T ~ 4) finish with a
// 16-step ballot bit-select run redundantly in every wave (no broadcast
// barriers). Histogram fallback for T > 64 keeps it exact. Non-temporal
// stores: out is write-once -> stream to HBM, no L3 dirty-allocate churn.
// (nt store via native ext_vector_type: builtin rejects HIP_vector_type.)

#define DIM  4096
#define EPL  8              // elems per lane: 8 waves * 64 lanes * 8 = 4096
#define NC0  16             // pass-0 histogram replicas
#define CPAD 260            // replica stride (ints): 16B-aligned, bank-shifted

typedef float nfloat4 __attribute__((ext_vector_type(4)));

__device__ __forceinline__ void nt_store4(float4* p, const float4 o) {
    nfloat4 n; n.x = o.x; n.y = o.y; n.z = o.z; n.w = o.w;
    __builtin_nontemporal_store(n, (nfloat4*)p);
}

struct Shared {
    int hist0[2][NC0 * CPAD];   // pass-0 replicas, per row
    int hist1[2][256];          // pass-1, per row
    int histf[2][256];          // fallback bytes 1,0 (shared, re-zeroed)
    unsigned int surv[2][64];
    int scnt[2];
    int wtie[8];
};

__device__ __forceinline__ void select_bin(const int4 h, const int lane, const int kr,
                                           int& chosen, int& cumG, int& T) {
    // h = this lane's 4 bins (4*lane .. 4*lane+3). Returns bin holding the
    // kr-th largest, count strictly greater (cumG), and that bin's count (T).
    const int s3 = h.w, s2 = h.z + s3, s1 = h.y + s2, s0 = h.x + s1;
    int v = s0;
    #pragma unroll
    for (int off = 1; off < 64; off <<= 1) {
        int t = __shfl_down(v, off, 64);
        if (lane + off < 64) v += t;
    }
    const int inc = v - s0;                       // totals of lanes > l
    const int S0 = s0 + inc, S1 = s1 + inc, S2 = s2 + inc, S3 = s3 + inc;
    int ci, cg, Tl;
    if      (S3 >= kr) { ci = 3; cg = inc; Tl = h.w; }
    else if (S2 >= kr) { ci = 2; cg = S3;  Tl = h.z; }
    else if (S1 >= kr) { ci = 1; cg = S2;  Tl = h.y; }
    else               { ci = 0; cg = S1;  Tl = h.x; }
    const bool has = (S0 >= kr) && (inc < kr);    // exactly one lane true
    const unsigned long long m = __ballot(has);
    const int src = __ffsll((unsigned long long)m) - 1;
    chosen = __shfl((lane << 2) + ci, src, 64);
    cumG   = __shfl(cg, src, 64);
    T      = __shfl(Tl, src, 64);
}

template <int R>
__device__ __forceinline__ void process_row(const unsigned int (&u)[EPL], Shared& sm,
                                            float4* __restrict__ outr4,
                                            const int k0, const int lane, const int w) {
    // ---- pass 0: replicated histogram of top byte (replica per half-wave) --
    const int c0 = ((w << 1) | (lane & 1)) * CPAD;
    #pragma unroll
    for (int j = 0; j < EPL; ++j)
        atomicAdd(&sm.hist0[R][c0 + (u[j] >> 24)], 1);
    __syncthreads();

    int kr = k0;
    unsigned int pfx;
    int T;
    {   // select 0 (all waves redundantly; identical LDS data)
        int4 h; h.x = 0; h.y = 0; h.z = 0; h.w = 0;
        #pragma unroll
        for (int c = 0; c < NC0; ++c) {
            const int4 t = *(const int4*)&sm.hist0[R][c * CPAD + (lane << 2)];
            h.x += t.x; h.y += t.y; h.z += t.z; h.w += t.w;
        }
        int ch, cg, Tx;
        select_bin(h, lane, kr, ch, cg, Tx);
        kr -= cg;
        pfx = ((unsigned int)ch) << 24;
    }

    // ---- pass 1: byte 2 among survivors (sparse -> single copy) ----
    #pragma unroll
    for (int j = 0; j < EPL; ++j)
        if ((u[j] & 0xFF000000u) == pfx)
            atomicAdd(&sm.hist1[R][(u[j] >> 16) & 255u], 1);
    __syncthreads();
    {
        const int4 h = *(const int4*)&sm.hist1[R][lane << 2];
        int ch, cg, Tx;
        select_bin(h, lane, kr, ch, cg, Tx);
        kr -= cg;
        pfx |= ((unsigned int)ch) << 16;
        T = Tx;
    }

    unsigned int thr;
    if (T <= 64) {
        // ---- common: compact survivors, ballot bit-select low 16 bits ----
        #pragma unroll
        for (int j = 0; j < EPL; ++j)
            if ((u[j] & 0xFFFF0000u) == pfx) {
                const int slot = atomicAdd(&sm.scnt[R], 1);
                sm.surv[R][slot] = u[j];
            }
        __syncthreads();
        const unsigned int vv = (lane < T) ? sm.surv[R][lane] : 0u;
        bool act = (lane < T);
        #pragma unroll
        for (int b = 15; b >= 0; --b) {
            const unsigned int bit = (vv >> b) & 1u;
            const unsigned long long m1 = __ballot(act && (bit != 0u));
            const int c = __popcll(m1);
            const bool ge = (c >= kr);
            act = act && (bit == (ge ? 1u : 0u));
            if (!ge) kr -= c;
        }
        const unsigned long long ma = __ballot(act);
        T   = __popcll(ma);
        thr = __shfl(vv, __ffsll((unsigned long long)ma) - 1, 64);
    } else {
        // ---- fallback (adversarial tie mass): histogram bytes 1 and 0 ----
        #pragma unroll
        for (int j = 0; j < EPL; ++j)
            if ((u[j] & 0xFFFF0000u) == pfx)
                atomicAdd(&sm.histf[0][(u[j] >> 8) & 255u], 1);
        __syncthreads();
        {
            const int4 h = *(const int4*)&sm.histf[0][lane << 2];
            int ch, cg, Tx;
            select_bin(h, lane, kr, ch, cg, Tx);
            kr -= cg;
            pfx |= ((unsigned int)ch) << 8;
        }
        #pragma unroll
        for (int j = 0; j < EPL; ++j)
            if ((u[j] & 0xFFFFFF00u) == pfx)
                atomicAdd(&sm.histf[1][u[j] & 255u], 1);
        __syncthreads();
        {
            const int4 h = *(const int4*)&sm.histf[1][lane << 2];
            int ch, cg, Tx;
            select_bin(h, lane, kr, ch, cg, Tx);
            kr -= cg;
            thr = pfx | (unsigned int)ch;
            T = Tx;
        }
        // re-zero histf for possible row-1 fallback
        __syncthreads();
        ((int*)sm.histf)[(w << 6) | lane] = 0;   // 512 ints, 512 threads
        __syncthreads();
    }
    // thr = k-th largest key; kr = ties to select; T = total ties (uniform).

    if (kr == T) {
        // All threshold ties selected: pure >= mask from registers.
        #pragma unroll
        for (int i = 0; i < 2; ++i) {
            float4 o;
            o.x = (u[4*i+0] >= thr) ? 1.0f : 0.0f;
            o.y = (u[4*i+1] >= thr) ? 1.0f : 0.0f;
            o.z = (u[4*i+2] >= thr) ? 1.0f : 0.0f;
            o.w = (u[4*i+3] >= thr) ? 1.0f : 0.0f;
            nt_store4(&outr4[(w << 7) + (i << 6) + lane], o);
        }
    } else {
        // Rare: rank exact ties in ascending global index order.
        int eqtot = 0;
        #pragma unroll
        for (int j = 0; j < EPL; ++j) eqtot += (u[j] == thr) ? 1 : 0;
        int vv = eqtot;
        #pragma unroll
        for (int off = 1; off < 64; off <<= 1) {
            int t = __shfl_up(vv, off, 64);
            if (lane >= off) vv += t;
        }
        if (lane == 63) sm.wtie[w] = vv;
        __syncthreads();
        int base = 0;
        #pragma unroll
        for (int ww = 0; ww < 8; ++ww) if (ww < w) base += sm.wtie[ww];

        #pragma unroll
        for (int i = 0; i < 2; ++i) {
            const int e0 = (u[4*i+0] == thr) ? 1 : 0;
            const int e1 = (u[4*i+1] == thr) ? 1 : 0;
            const int e2 = (u[4*i+2] == thr) ? 1 : 0;
            const int e3 = (u[4*i+3] == thr) ? 1 : 0;
            const int ti = e0 + e1 + e2 + e3;
            int vi = ti;
            #pragma unroll
            for (int off = 1; off < 64; off <<= 1) {
                int t = __shfl_up(vi, off, 64);
                if (lane >= off) vi += t;
            }
            int r = base + (vi - ti);
            const int tot = __shfl(vi, 63, 64);
            float4 o;
            o.x = (u[4*i+0] > thr) ? 1.0f : ((e0 && r < kr) ? 1.0f : 0.0f); r += e0;
            o.y = (u[4*i+1] > thr) ? 1.0f : ((e1 && r < kr) ? 1.0f : 0.0f); r += e1;
            o.z = (u[4*i+2] > thr) ? 1.0f : ((e2 && r < kr) ? 1.0f : 0.0f); r += e2;
            o.w = (u[4*i+3] > thr) ? 1.0f : ((e3 && r < kr) ? 1.0f : 0.0f); r += e3;
            nt_store4(&outr4[(w << 7) + (i << 6) + lane], o);
            base += tot;
        }
    }
}

__global__ void __launch_bounds__(512)
topk_mask_kernel(const float* __restrict__ x, const int* __restrict__ k0ptr,
                 float* __restrict__ out, const int bs) {
    const int tid  = threadIdx.x;
    const int lane = tid & 63;
    const int w    = tid >> 6;                    // 0..7
    const int row0 = (int)(blockIdx.x << 1);
    const int row1 = row0 + 1;
    const bool has1 = (row1 < bs);

    __shared__ Shared sm;

    const float4* xr0 = (const float4*)(x + (size_t)row0 * DIM);
    const float4* xr1 = (const float4*)(x + (size_t)(has1 ? row1 : row0) * DIM);
    float4* or0 = (float4*)(out + (size_t)row0 * DIM);
    float4* or1 = (float4*)(out + (size_t)row1 * DIM);

    const int k0 = k0ptr[0];                      // uniform scalar load

    // Wave w owns elements [512w, 512w+512) of each row; elem of u[4i+c] is
    // 512w + 256i + 4*lane + c -> lexicographic (w,i,lane,c) = ascending idx.
    const int base = (w << 7) + lane;
    const float4 f0 = xr0[base];
    const float4 f1 = xr0[base + 64];
    const float4 g0 = xr1[base];
    const float4 g1 = xr1[base + 64];

    // Zero LDS while all 4 row-loads are in flight.
    for (int t = tid; t < 2 * NC0 * CPAD; t += 512) ((int*)sm.hist0)[t] = 0;
    ((int*)sm.hist1)[tid] = 0;                    // 2*256 = 512 ints
    ((int*)sm.histf)[tid] = 0;                    // 2*256 = 512 ints
    if (tid < 2) sm.scnt[tid] = 0;

    // fp32 -> sortable-ascending uint32 (registers, static indexing).
    unsigned int u[EPL], v[EPL];
#define MAP4(arr, i, vv)                                                    \
    {                                                                       \
        unsigned int b0 = __float_as_uint((vv).x);                          \
        unsigned int b1 = __float_as_uint((vv).y);                          \
        unsigned int b2 = __float_as_uint((vv).z);                          \
        unsigned int b3 = __float_as_uint((vv).w);                          \
        arr[4*(i)+0] = (b0 & 0x80000000u) ? ~b0 : (b0 | 0x80000000u);       \
        arr[4*(i)+1] = (b1 & 0x80000000u) ? ~b1 : (b1 | 0x80000000u);       \
        arr[4*(i)+2] = (b2 & 0x80000000u) ? ~b2 : (b2 | 0x80000000u);       \
        arr[4*(i)+3] = (b3 & 0x80000000u) ? ~b3 : (b3 | 0x80000000u);       \
    }
    MAP4(u, 0, f0) MAP4(u, 1, f1)
    MAP4(v, 0, g0) MAP4(v, 1, g1)
#undef MAP4

    __syncthreads();                              // zeros visible

    process_row<0>(u, sm, or0, k0, lane, w);
    if (has1) process_row<1>(v, sm, or1, k0, lane, w);
}

extern "C" void kernel_launch(void* const* d_in, const int* in_sizes, int n_in,
                              void* d_out, int out_size, void* d_ws, size_t ws_size,
                              hipStream_t stream) {
    const float* x   = (const float*)d_in[0];
    // d_in[1] = k vector [bs] (unused: forward mask depends only on k0)
    const int*   k0  = (const int*)d_in[2];
    float*       out = (float*)d_out;

    const int bs = in_sizes[1];                   // dim == 4096 (reference)
    const int grid = (bs + 1) >> 1;               // 2 rows per block
    topk_mask_kernel<<<grid, 512, 0, stream>>>(x, k0, out, bs);
}